// Round 1
// baseline (2313.896 us; speedup 1.0000x reference)
//
#include <hip/hip_runtime.h>
#include <hip/hip_bf16.h>

#define B_    8
#define N_    2352
#define D_    512
#define SENT  48
#define PAIRS 512
#define NERL  16
#define REL   32

// ---------------------------------------------------------------- denom ----
// denom[b,n] = sum_m adj[b,n,m] + 1.   One wave per row, float4 loads.
__global__ __launch_bounds__(256) void denom_kernel(const float* __restrict__ adj,
                                                    float* __restrict__ denom) {
  int wave = threadIdx.x >> 6;
  int lane = threadIdx.x & 63;
  int row  = blockIdx.x * 4 + wave;
  if (row >= B_ * N_) return;
  const float4* a = (const float4*)(adj + (size_t)row * N_);
  float s = 0.f;
  for (int i = lane; i < N_ / 4; i += 64) {   // 588 float4 per row
    float4 v = a[i];
    s += v.x + v.y + v.z + v.w;
  }
  for (int o = 32; o > 0; o >>= 1) s += __shfl_down(s, o);
  if (lane == 0) denom[row] = s + 1.0f;
}

// ------------------------------------------------------------- gemm_adj ----
// S[b] = adj[b] @ X[b] + X[b].   M=K=2352 (edges), Ncols=512.
// 128x128 tile, BK=32, 256 threads, 8x8 microtile (cols split 4+4 at +64).
__global__ __launch_bounds__(256) void gemm_adj(const float* __restrict__ adj,
                                                const float* __restrict__ X,
                                                float* __restrict__ S) {
  const int b  = blockIdx.z;
  const int m0 = blockIdx.x * 128;
  const int n0 = blockIdx.y * 128;
  const float* A  = adj + (size_t)b * N_ * N_;
  const float* Xb = X   + (size_t)b * N_ * D_;
  float*       Sb = S   + (size_t)b * N_ * D_;

  __shared__ float As[32][132];   // transposed: As[k][m], pad keeps 16B align
  __shared__ float Bs[32][128];

  const int t  = threadIdx.x;
  const int tx = t & 15, ty = t >> 4;

  float acc[8][8];
  #pragma unroll
  for (int i = 0; i < 8; ++i)
    #pragma unroll
    for (int j = 0; j < 8; ++j) acc[i][j] = 0.f;

  for (int k0 = 0; k0 < N_; k0 += 32) {
    #pragma unroll
    for (int i = 0; i < 4; ++i) {           // A tile: 128 rows x 32 cols
      int idx = t + i * 256;                // 0..1023
      int r   = idx >> 3;                   // 0..127
      int c4  = (idx & 7) * 4;              // 0..28
      int gm = m0 + r, gk = k0 + c4;
      float4 v = {0.f, 0.f, 0.f, 0.f};
      if (gm < N_ && gk < N_) v = *(const float4*)(A + (size_t)gm * N_ + gk);
      As[c4 + 0][r] = v.x; As[c4 + 1][r] = v.y;
      As[c4 + 2][r] = v.z; As[c4 + 3][r] = v.w;
    }
    #pragma unroll
    for (int i = 0; i < 4; ++i) {           // B tile: 32 rows x 128 cols
      int idx = t + i * 256;
      int r   = idx >> 5;                   // 0..31
      int c4  = (idx & 31) * 4;             // 0..124
      int gk  = k0 + r;
      float4 v = {0.f, 0.f, 0.f, 0.f};
      if (gk < N_) v = *(const float4*)(Xb + (size_t)gk * D_ + n0 + c4);
      *(float4*)&Bs[r][c4] = v;
    }
    __syncthreads();
    #pragma unroll
    for (int kk = 0; kk < 32; ++kk) {
      float a[8], bb[8];
      *(float4*)&a[0]  = *(const float4*)&As[kk][ty * 8];
      *(float4*)&a[4]  = *(const float4*)&As[kk][ty * 8 + 4];
      *(float4*)&bb[0] = *(const float4*)&Bs[kk][tx * 4];
      *(float4*)&bb[4] = *(const float4*)&Bs[kk][64 + tx * 4];
      #pragma unroll
      for (int i = 0; i < 8; ++i)
        #pragma unroll
        for (int j = 0; j < 8; ++j) acc[i][j] = fmaf(a[i], bb[j], acc[i][j]);
    }
    __syncthreads();
  }
  #pragma unroll
  for (int i = 0; i < 8; ++i) {
    int gm = m0 + ty * 8 + i;
    if (gm >= N_) continue;
    int gn1 = n0 + tx * 4;
    int gn2 = n0 + 64 + tx * 4;
    float4 x1 = *(const float4*)(Xb + (size_t)gm * D_ + gn1);
    float4 x2 = *(const float4*)(Xb + (size_t)gm * D_ + gn2);
    float4 o1 = {acc[i][0] + x1.x, acc[i][1] + x1.y, acc[i][2] + x1.z, acc[i][3] + x1.w};
    float4 o2 = {acc[i][4] + x2.x, acc[i][5] + x2.y, acc[i][6] + x2.z, acc[i][7] + x2.w};
    *(float4*)(Sb + (size_t)gm * D_ + gn1) = o1;
    *(float4*)(Sb + (size_t)gm * D_ + gn2) = o2;
  }
}

// --------------------------------------------------------------- gemm_w ----
// G = relu((Sin @ W + 2*bias) / denom).  M=18816 exact, K=N=512 exact.
__global__ __launch_bounds__(256) void gemm_w(const float* __restrict__ Sin,
                                              const float* __restrict__ W,
                                              const float* __restrict__ bias,
                                              const float* __restrict__ denom,
                                              float* __restrict__ G) {
  const int m0 = blockIdx.x * 128;
  const int n0 = blockIdx.y * 128;
  __shared__ float As[32][132];
  __shared__ float Bs[32][128];
  const int t  = threadIdx.x;
  const int tx = t & 15, ty = t >> 4;

  float acc[8][8];
  #pragma unroll
  for (int i = 0; i < 8; ++i)
    #pragma unroll
    for (int j = 0; j < 8; ++j) acc[i][j] = 0.f;

  for (int k0 = 0; k0 < D_; k0 += 32) {
    #pragma unroll
    for (int i = 0; i < 4; ++i) {
      int idx = t + i * 256;
      int r = idx >> 3, c4 = (idx & 7) * 4;
      float4 v = *(const float4*)(Sin + (size_t)(m0 + r) * D_ + k0 + c4);
      As[c4 + 0][r] = v.x; As[c4 + 1][r] = v.y;
      As[c4 + 2][r] = v.z; As[c4 + 3][r] = v.w;
    }
    #pragma unroll
    for (int i = 0; i < 4; ++i) {
      int idx = t + i * 256;
      int r = idx >> 5, c4 = (idx & 31) * 4;
      *(float4*)&Bs[r][c4] = *(const float4*)(W + (size_t)(k0 + r) * D_ + n0 + c4);
    }
    __syncthreads();
    #pragma unroll
    for (int kk = 0; kk < 32; ++kk) {
      float a[8], bb[8];
      *(float4*)&a[0]  = *(const float4*)&As[kk][ty * 8];
      *(float4*)&a[4]  = *(const float4*)&As[kk][ty * 8 + 4];
      *(float4*)&bb[0] = *(const float4*)&Bs[kk][tx * 4];
      *(float4*)&bb[4] = *(const float4*)&Bs[kk][64 + tx * 4];
      #pragma unroll
      for (int i = 0; i < 8; ++i)
        #pragma unroll
        for (int j = 0; j < 8; ++j) acc[i][j] = fmaf(a[i], bb[j], acc[i][j]);
    }
    __syncthreads();
  }
  #pragma unroll
  for (int i = 0; i < 8; ++i) {
    int gm = m0 + ty * 8 + i;
    float dn = denom[gm];
    #pragma unroll
    for (int half = 0; half < 2; ++half) {
      int gn = n0 + half * 64 + tx * 4;
      float4 o;
      o.x = fmaxf(0.f, (acc[i][half * 4 + 0] + 2.f * bias[gn + 0]) / dn);
      o.y = fmaxf(0.f, (acc[i][half * 4 + 1] + 2.f * bias[gn + 1]) / dn);
      o.z = fmaxf(0.f, (acc[i][half * 4 + 2] + 2.f * bias[gn + 2]) / dn);
      o.w = fmaxf(0.f, (acc[i][half * 4 + 3] + 2.f * bias[gn + 3]) / dn);
      *(float4*)(G + (size_t)gm * D_ + gn) = o;
    }
  }
}

// ------------------------------------------------------------- gemm_cat ----
// logits = concat([g0,g1],-1) @ out_w + out_b.  M=18816, K=1024, N=512.
__global__ __launch_bounds__(256) void gemm_cat(const float* __restrict__ g0,
                                                const float* __restrict__ g1,
                                                const float* __restrict__ W,
                                                const float* __restrict__ bias,
                                                float* __restrict__ out) {
  const int m0 = blockIdx.x * 128;
  const int n0 = blockIdx.y * 128;
  __shared__ float As[32][132];
  __shared__ float Bs[32][128];
  const int t  = threadIdx.x;
  const int tx = t & 15, ty = t >> 4;

  float acc[8][8];
  #pragma unroll
  for (int i = 0; i < 8; ++i)
    #pragma unroll
    for (int j = 0; j < 8; ++j) acc[i][j] = 0.f;

  for (int k0 = 0; k0 < 2 * D_; k0 += 32) {
    const float* Asrc = (k0 < D_) ? g0 : g1;
    int kc = k0 & (D_ - 1);
    #pragma unroll
    for (int i = 0; i < 4; ++i) {
      int idx = t + i * 256;
      int r = idx >> 3, c4 = (idx & 7) * 4;
      float4 v = *(const float4*)(Asrc + (size_t)(m0 + r) * D_ + kc + c4);
      As[c4 + 0][r] = v.x; As[c4 + 1][r] = v.y;
      As[c4 + 2][r] = v.z; As[c4 + 3][r] = v.w;
    }
    #pragma unroll
    for (int i = 0; i < 4; ++i) {
      int idx = t + i * 256;
      int r = idx >> 5, c4 = (idx & 31) * 4;
      *(float4*)&Bs[r][c4] = *(const float4*)(W + (size_t)(k0 + r) * D_ + n0 + c4);
    }
    __syncthreads();
    #pragma unroll
    for (int kk = 0; kk < 32; ++kk) {
      float a[8], bb[8];
      *(float4*)&a[0]  = *(const float4*)&As[kk][ty * 8];
      *(float4*)&a[4]  = *(const float4*)&As[kk][ty * 8 + 4];
      *(float4*)&bb[0] = *(const float4*)&Bs[kk][tx * 4];
      *(float4*)&bb[4] = *(const float4*)&Bs[kk][64 + tx * 4];
      #pragma unroll
      for (int i = 0; i < 8; ++i)
        #pragma unroll
        for (int j = 0; j < 8; ++j) acc[i][j] = fmaf(a[i], bb[j], acc[i][j]);
    }
    __syncthreads();
  }
  #pragma unroll
  for (int i = 0; i < 8; ++i) {
    int gm = m0 + ty * 8 + i;
    #pragma unroll
    for (int half = 0; half < 2; ++half) {
      int gn = n0 + half * 64 + tx * 4;
      float4 o;
      o.x = acc[i][half * 4 + 0] + bias[gn + 0];
      o.y = acc[i][half * 4 + 1] + bias[gn + 1];
      o.z = acc[i][half * 4 + 2] + bias[gn + 2];
      o.w = acc[i][half * 4 + 3] + bias[gn + 3];
      *(float4*)(out + (size_t)gm * D_ + gn) = o;
    }
  }
}

// ------------------------------------------------------------- ner head ----
// ner_logits[b,t,:] = concat([ner[b,t], logits[b,t]]) @ ner_w + ner_b.
// One wave per row (384 rows), 16 outputs each.
__global__ __launch_bounds__(64) void ner_kernel(const float* __restrict__ ner,
                                                 const float* __restrict__ logits,
                                                 const float* __restrict__ nw,
                                                 const float* __restrict__ nb,
                                                 float* __restrict__ out) {
  int r = blockIdx.x;                 // 0..383
  int b = r / SENT, tp = r % SENT;
  int lane = threadIdx.x;
  const float* nrow = ner    + ((size_t)b * SENT + tp) * D_;
  const float* lrow = logits + ((size_t)b * N_   + tp) * D_;
  float rv[16];
  #pragma unroll
  for (int i = 0; i < 8; ++i) rv[i]     = nrow[lane + i * 64];
  #pragma unroll
  for (int i = 0; i < 8; ++i) rv[8 + i] = lrow[lane + i * 64];
  for (int j = 0; j < NERL; ++j) {
    float s = 0.f;
    #pragma unroll
    for (int i = 0; i < 16; ++i)
      s = fmaf(rv[i], nw[(size_t)(lane + i * 64) * NERL + j], s);   // i>=8 -> k=512+...
    for (int o = 32; o > 0; o >>= 1) s += __shfl_down(s, o);
    if (lane == 0) out[r * NERL + j] = s + nb[j];
  }
}

// ----------------------------------------------------------- pair + re -----
// avg[p] = mean of 4 gathered logits rows; re_logits = concat([re_feat,avg])@re_w+re_b.
__global__ __launch_bounds__(256) void pair_kernel(const float* __restrict__ logits,
                                                   const float* __restrict__ refeat,
                                                   const float* __restrict__ rw,
                                                   const float* __restrict__ rb,
                                                   const int* __restrict__ ps,
                                                   const int* __restrict__ hs,
                                                   const int* __restrict__ ts,
                                                   float* __restrict__ out) {
  int p = blockIdx.x;
  __shared__ float avg[D_];
  int b = ps[p], h = hs[p], tt = ts[p];
  const float* base = logits + (size_t)b * N_ * D_;
  const float* r00 = base + (size_t)((h + 1) * SENT + tt) * D_;
  const float* r01 = base + (size_t)((h + 1) * SENT + tt + 1) * D_;
  const float* r10 = base + (size_t)((h + 2) * SENT + tt) * D_;
  const float* r11 = base + (size_t)((h + 2) * SENT + tt + 1) * D_;
  for (int d = threadIdx.x; d < D_; d += 256)
    avg[d] = 0.25f * (r00[d] + r01[d] + r10[d] + r11[d]);
  __syncthreads();
  int wave = threadIdx.x >> 6, lane = threadIdx.x & 63;
  const float* rf = refeat + (size_t)p * D_;
  for (int jj = 0; jj < 8; ++jj) {
    int j = wave * 8 + jj;
    float s = 0.f;
    #pragma unroll
    for (int i = 0; i < 8; ++i) {
      int k = lane + i * 64;
      s = fmaf(rf[k],  rw[(size_t)k * REL + j], s);
      s = fmaf(avg[k], rw[(size_t)(k + D_) * REL + j], s);
    }
    for (int o = 32; o > 0; o >>= 1) s += __shfl_down(s, o);
    if (lane == 0) out[p * REL + j] = s + rb[j];
  }
}

// --------------------------------------------------------------- launch ----
extern "C" void kernel_launch(void* const* d_in, const int* in_sizes, int n_in,
                              void* d_out, int out_size, void* d_ws, size_t ws_size,
                              hipStream_t stream) {
  const float* inputs = (const float*)d_in[0];
  const float* ner    = (const float*)d_in[1];
  const float* refeat = (const float*)d_in[2];
  const float* adj    = (const float*)d_in[3];
  const float* W0w    = (const float*)d_in[4];
  const float* W0b    = (const float*)d_in[5];
  const float* W1w    = (const float*)d_in[6];
  const float* W1b    = (const float*)d_in[7];
  const float* outw   = (const float*)d_in[8];
  const float* outb   = (const float*)d_in[9];
  const float* nerw   = (const float*)d_in[10];
  const float* nerb   = (const float*)d_in[11];
  const float* rew    = (const float*)d_in[12];
  const float* reb    = (const float*)d_in[13];
  const int*   ps     = (const int*)d_in[14];
  const int*   hs     = (const int*)d_in[15];
  const int*   ts     = (const int*)d_in[16];
  (void)in_sizes; (void)n_in; (void)out_size; (void)ws_size;

  const size_t BUF = (size_t)B_ * N_ * D_ * sizeof(float);   // 38,535,168 B
  char* ws = (char*)d_ws;
  float* denom = (float*)ws;                    // 18816 floats = 75264 B
  float* S     = (float*)(ws + 75264);
  float* g0    = (float*)(ws + 75264 + BUF);
  float* g1    = (float*)(ws + 75264 + 2 * BUF);
  float* logits = S;                            // reuse S after layer GEMMs
  float* outp  = (float*)d_out;

  denom_kernel<<<(B_ * N_ + 3) / 4, 256, 0, stream>>>(adj, denom);

  dim3 gAdj((N_ + 127) / 128, D_ / 128, B_);    // (19, 4, 8)
  dim3 gW((B_ * N_) / 128, D_ / 128);           // (147, 4)

  gemm_adj<<<gAdj, 256, 0, stream>>>(adj, inputs, S);
  gemm_w  <<<gW,   256, 0, stream>>>(S, W0w, W0b, denom, g0);
  gemm_adj<<<gAdj, 256, 0, stream>>>(adj, g0, S);
  gemm_w  <<<gW,   256, 0, stream>>>(S, W1w, W1b, denom, g1);
  gemm_cat<<<gW,   256, 0, stream>>>(g0, g1, outw, outb, logits);

  ner_kernel <<<B_ * SENT, 64,  0, stream>>>(ner, logits, nerw, nerb, outp);
  pair_kernel<<<PAIRS,     256, 0, stream>>>(logits, refeat, rew, reb, ps, hs, ts,
                                             outp + B_ * SENT * NERL);
}

// Round 2
// 509.683 us; speedup vs baseline: 4.5399x; 4.5399x over previous
//
#include <hip/hip_runtime.h>
#include <hip/hip_bf16.h>

#define B_    8
#define NP    2352
#define D_    512
#define SENT  48
#define PAIRS 512
#define NERL  16
#define REL   32
#define MTOT  (B_*NP)   // 18816

typedef unsigned short u16;
typedef __bf16 bf16x8 __attribute__((ext_vector_type(8)));
typedef float  f32x4  __attribute__((ext_vector_type(4)));

__device__ __forceinline__ u16 f2b(float f) {
  union { float f; unsigned u; } c; c.f = f;
  unsigned u = c.u;
  u += 0x7fffu + ((u >> 16) & 1u);           // round-to-nearest-even
  return (u16)(u >> 16);
}
__device__ __forceinline__ float b2f(u16 h) {
  union { unsigned u; float f; } c; c.u = ((unsigned)h) << 16;
  return c.f;
}
__device__ __forceinline__ void gload16(const u16* g, u16* lds) {
  __builtin_amdgcn_global_load_lds(
      (const __attribute__((address_space(1))) unsigned*)g,
      (__attribute__((address_space(3))) unsigned*)lds, 16, 0, 0);
}

// ----------------------------------------------------------------- zero ----
__global__ void zero_zp(u16* zp) { zp[threadIdx.x] = 0; }

// ------------------------------------------------------------- prep_adj ----
// adj f32 -> adj bf16 (same layout) + rdenom = 1/(rowsum+1). One block/row.
__global__ __launch_bounds__(256) void prep_adj(const float* __restrict__ adj,
                                                u16* __restrict__ adjb,
                                                float* __restrict__ rdenom) {
  const int row = blockIdx.x;                 // 0..18815
  const float4* src = (const float4*)(adj + (size_t)row * NP);
  ushort4* dst = (ushort4*)(adjb + (size_t)row * NP);
  float s = 0.f;
  for (int i = threadIdx.x; i < NP / 4; i += 256) {
    float4 v = src[i];
    s += (v.x + v.y) + (v.z + v.w);
    ushort4 o; o.x = f2b(v.x); o.y = f2b(v.y); o.z = f2b(v.z); o.w = f2b(v.w);
    dst[i] = o;
  }
  #pragma unroll
  for (int o = 32; o > 0; o >>= 1) s += __shfl_down(s, o, 64);
  __shared__ float red[4];
  int w = threadIdx.x >> 6, l = threadIdx.x & 63;
  if (l == 0) red[w] = s;
  __syncthreads();
  if (threadIdx.x == 0)
    rdenom[row] = 1.f / (red[0] + red[1] + red[2] + red[3] + 1.f);
}

// ----------------------------------------------------- transpose-convert ---
// in [R][C] (f32 or bf16) -> out [C][R] bf16.  64x64 tiles, 256 threads.
template<int INF32>
__global__ __launch_bounds__(256) void tcvt(const void* __restrict__ in_,
                                            u16* __restrict__ out,
                                            int R, int C, size_t inb, size_t outb) {
  __shared__ u16 tile[64][65];
  const int b  = blockIdx.z;
  const int r0 = blockIdx.x * 64, c0 = blockIdx.y * 64;
  const int t  = threadIdx.x;
  const int tr = t >> 4, tc = (t & 15) * 4;
  #pragma unroll
  for (int i = 0; i < 4; ++i) {
    int rl = i * 16 + tr;
    int r  = r0 + rl;
    if (r < R) {
      if (INF32) {
        const float* in = (const float*)in_ + (size_t)b * inb + (size_t)r * C + c0 + tc;
        float4 v = *(const float4*)in;
        tile[rl][tc + 0] = f2b(v.x); tile[rl][tc + 1] = f2b(v.y);
        tile[rl][tc + 2] = f2b(v.z); tile[rl][tc + 3] = f2b(v.w);
      } else {
        const u16* in = (const u16*)in_ + (size_t)b * inb + (size_t)r * C + c0 + tc;
        ushort4 v = *(const ushort4*)in;
        tile[rl][tc + 0] = v.x; tile[rl][tc + 1] = v.y;
        tile[rl][tc + 2] = v.z; tile[rl][tc + 3] = v.w;
      }
    }
  }
  __syncthreads();
  const int c  = t >> 2;
  const int rb = (t & 3) * 16;
  u16* orow = out + (size_t)b * outb + (size_t)(c0 + c) * R + r0;
  #pragma unroll
  for (int i = 0; i < 4; ++i) {
    int rl = rb + i * 4;
    int r  = r0 + rl;
    if (r + 3 < R) {
      ushort4 v;
      v.x = tile[rl + 0][c]; v.y = tile[rl + 1][c];
      v.z = tile[rl + 2][c]; v.w = tile[rl + 3][c];
      *(ushort4*)(orow + rl) = v;
    } else {
      for (int j = 0; j < 4; ++j)
        if (r + j < R) orow[rl + j] = tile[rl + j][c];
    }
  }
}

// ------------------------------------------------------------- MFMA GEMM ---
// C[m][n] = sum_k A[m][k]*B[n][k]  (both operands k-major), 128x128 tile,
// BK=32, 4 waves (2x2), each wave 64x64 via 4x4 16x16x32 bf16 MFMA frags.
// MODE 0: adj GEMM  (per-batch; epilogue += x from Xt; out bf16 S)
// MODE 1: W GEMM    (epilogue (acc+2b)*rdenom, relu; out bf16 g)
// MODE 2: cat GEMM  (A = concat(g0,g1) over k; epilogue +bias; out bf16)
template<int MODE>
__global__ __launch_bounds__(256) void gemm_bf(
    const u16* __restrict__ A, const u16* __restrict__ A2,
    const u16* __restrict__ Bm, const u16* __restrict__ Xt,
    const float* __restrict__ bias, const float* __restrict__ rdenom,
    const u16* __restrict__ zp, u16* __restrict__ out)
{
  constexpr int KACT   = (MODE == 0) ? NP : (MODE == 1 ? 512 : 1024);
  constexpr int KSTEPS = (KACT + 31) / 32;
  constexpr int LDB    = KACT;
  constexpr int LDA    = (MODE == 0) ? NP : 512;

  const int m0 = blockIdx.x * 128;
  const int n0 = blockIdx.y * 128;
  const u16* Ab = A;
  const u16* Bb = Bm;
  const u16* Xb = Xt;
  size_t outBase = 0;
  if constexpr (MODE == 0) {
    const int b = blockIdx.z;
    Ab = A  + (size_t)b * NP * NP;
    Bb = Bm + (size_t)b * 512 * NP;
    Xb = Xt + (size_t)b * 512 * NP;
    outBase = (size_t)b * NP * 512;
  }

  __shared__ u16 As[128 * 32];   // 8 KB, [row][32k], k-slot XOR-swizzled
  __shared__ u16 Bs[128 * 32];   // 8 KB

  const int t  = threadIdx.x;
  const int w  = t >> 6, l = t & 63;
  const int wm = w >> 1, wn = w & 1;
  const int lr = l & 15, lq = l >> 4;

  f32x4 acc[4][4];
  #pragma unroll
  for (int i = 0; i < 4; ++i)
    #pragma unroll
    for (int j = 0; j < 4; ++j)
      acc[i][j] = (f32x4){0.f, 0.f, 0.f, 0.f};

  const int rA = w * 16 + (l >> 2);   // local row staged by this lane (issue 0)
  const int sl = l & 3;               // k-slot (pre-swizzle)

  for (int ks = 0; ks < KSTEPS; ++ks) {
    const int k0 = ks * 32;
    #pragma unroll
    for (int i = 0; i < 2; ++i) {
      const int r  = i * 64 + rA;                         // 0..127
      const int gk = k0 + ((sl ^ ((r >> 1) & 3)) << 3);   // swizzled source k
      { // ---- A tile
        int gm = m0 + r;
        if (MODE == 0 && gm > NP - 1) gm = NP - 1;        // M-tail clamp
        const u16* src;
        if constexpr (MODE == 2) {
          src = (gk < 512) ? (A  + (size_t)gm * 512 + gk)
                           : (A2 + (size_t)gm * 512 + (gk - 512));
        } else {
          src = Ab + (size_t)gm * LDA + gk;
        }
        if (gk >= KACT) src = zp;                         // K-tail -> zeros
        gload16(src, As + i * 2048 + w * 512);
      }
      { // ---- B tile
        const int gn = n0 + r;
        const u16* src = Bb + (size_t)gn * LDB + gk;
        if (gk >= KACT) src = zp;
        gload16(src, Bs + i * 2048 + w * 512);
      }
    }
    __syncthreads();
    bf16x8 af[4], bg[4];
    #pragma unroll
    for (int f = 0; f < 4; ++f) {
      const int ra = wm * 64 + f * 16 + lr;
      af[f] = *(const bf16x8*)(As + ra * 32 + ((lq ^ ((ra >> 1) & 3)) << 3));
      const int rb2 = wn * 64 + f * 16 + lr;
      bg[f] = *(const bf16x8*)(Bs + rb2 * 32 + ((lq ^ ((rb2 >> 1) & 3)) << 3));
    }
    #pragma unroll
    for (int mf = 0; mf < 4; ++mf)
      #pragma unroll
      for (int nf = 0; nf < 4; ++nf)
        acc[mf][nf] = __builtin_amdgcn_mfma_f32_16x16x32_bf16(
            af[mf], bg[nf], acc[mf][nf], 0, 0, 0);
    __syncthreads();
  }

  // --------------------------------------------------------- epilogue ----
  #pragma unroll
  for (int mf = 0; mf < 4; ++mf) {
    const int gm0 = m0 + wm * 64 + mf * 16 + lq * 4;
    f32x4 rd;
    if constexpr (MODE == 1) rd = *(const f32x4*)(rdenom + gm0);
    #pragma unroll
    for (int nf = 0; nf < 4; ++nf) {
      const int gn = n0 + wn * 64 + nf * 16 + lr;
      if constexpr (MODE == 0) {
        const int xg = (gm0 > NP - 4) ? (NP - 4) : gm0;
        ushort4 xv = *(const ushort4*)(Xb + (size_t)gn * NP + xg);
        float xf0 = b2f(xv.x), xf1 = b2f(xv.y), xf2 = b2f(xv.z), xf3 = b2f(xv.w);
        float xf[4] = {xf0, xf1, xf2, xf3};
        #pragma unroll
        for (int r = 0; r < 4; ++r) {
          const int gm = gm0 + r;
          if (gm < NP)
            out[outBase + (size_t)gm * 512 + gn] = f2b(acc[mf][nf][r] + xf[r]);
        }
      } else if constexpr (MODE == 1) {
        const float bn = 2.f * bias[gn];
        #pragma unroll
        for (int r = 0; r < 4; ++r) {
          float v = (acc[mf][nf][r] + bn) * rd[r];
          v = fmaxf(v, 0.f);
          out[(size_t)(gm0 + r) * 512 + gn] = f2b(v);
        }
      } else {
        const float bn = bias[gn];
        #pragma unroll
        for (int r = 0; r < 4; ++r)
          out[(size_t)(gm0 + r) * 512 + gn] = f2b(acc[mf][nf][r] + bn);
      }
    }
  }
}

// ------------------------------------------------------------- ner head ----
__global__ __launch_bounds__(64) void ner_kernel(const float* __restrict__ ner,
                                                 const u16* __restrict__ logits,
                                                 const float* __restrict__ nw,
                                                 const float* __restrict__ nb,
                                                 float* __restrict__ out) {
  int r = blockIdx.x;                 // 0..383
  int b = r / SENT, tp = r % SENT;
  int lane = threadIdx.x;
  const float* nrow = ner    + ((size_t)b * SENT + tp) * D_;
  const u16*   lrow = logits + ((size_t)b * NP   + tp) * D_;
  float rv[16];
  #pragma unroll
  for (int i = 0; i < 8; ++i) rv[i]     = nrow[lane + i * 64];
  #pragma unroll
  for (int i = 0; i < 8; ++i) rv[8 + i] = b2f(lrow[lane + i * 64]);
  for (int j = 0; j < NERL; ++j) {
    float s = 0.f;
    #pragma unroll
    for (int i = 0; i < 16; ++i)
      s = fmaf(rv[i], nw[(size_t)(lane + i * 64) * NERL + j], s);
    for (int o = 32; o > 0; o >>= 1) s += __shfl_down(s, o);
    if (lane == 0) out[r * NERL + j] = s + nb[j];
  }
}

// ----------------------------------------------------------- pair + re -----
__global__ __launch_bounds__(256) void pair_kernel(const u16* __restrict__ logits,
                                                   const float* __restrict__ refeat,
                                                   const float* __restrict__ rw,
                                                   const float* __restrict__ rb,
                                                   const int* __restrict__ ps,
                                                   const int* __restrict__ hs,
                                                   const int* __restrict__ ts,
                                                   float* __restrict__ out) {
  int p = blockIdx.x;
  __shared__ float avg[D_];
  int b = ps[p], h = hs[p], tt = ts[p];
  const u16* base = logits + (size_t)b * NP * D_;
  const u16* r00 = base + (size_t)((h + 1) * SENT + tt) * D_;
  const u16* r01 = base + (size_t)((h + 1) * SENT + tt + 1) * D_;
  const u16* r10 = base + (size_t)((h + 2) * SENT + tt) * D_;
  const u16* r11 = base + (size_t)((h + 2) * SENT + tt + 1) * D_;
  for (int d = threadIdx.x; d < D_; d += 256)
    avg[d] = 0.25f * (b2f(r00[d]) + b2f(r01[d]) + b2f(r10[d]) + b2f(r11[d]));
  __syncthreads();
  int wave = threadIdx.x >> 6, lane = threadIdx.x & 63;
  const float* rf = refeat + (size_t)p * D_;
  for (int jj = 0; jj < 8; ++jj) {
    int j = wave * 8 + jj;
    float s = 0.f;
    #pragma unroll
    for (int i = 0; i < 8; ++i) {
      int k = lane + i * 64;
      s = fmaf(rf[k],  rw[(size_t)k * REL + j], s);
      s = fmaf(avg[k], rw[(size_t)(k + D_) * REL + j], s);
    }
    for (int o = 32; o > 0; o >>= 1) s += __shfl_down(s, o);
    if (lane == 0) out[p * REL + j] = s + rb[j];
  }
}

// --------------------------------------------------------------- launch ----
extern "C" void kernel_launch(void* const* d_in, const int* in_sizes, int n_in,
                              void* d_out, int out_size, void* d_ws, size_t ws_size,
                              hipStream_t stream) {
  const float* inputs = (const float*)d_in[0];
  const float* ner    = (const float*)d_in[1];
  const float* refeat = (const float*)d_in[2];
  const float* adj    = (const float*)d_in[3];
  const float* W0w    = (const float*)d_in[4];
  const float* W0b    = (const float*)d_in[5];
  const float* W1w    = (const float*)d_in[6];
  const float* W1b    = (const float*)d_in[7];
  const float* outw   = (const float*)d_in[8];
  const float* outb   = (const float*)d_in[9];
  const float* nerw   = (const float*)d_in[10];
  const float* nerb   = (const float*)d_in[11];
  const float* rew    = (const float*)d_in[12];
  const float* reb    = (const float*)d_in[13];
  const int*   ps     = (const int*)d_in[14];
  const int*   hs     = (const int*)d_in[15];
  const int*   ts     = (const int*)d_in[16];
  (void)in_sizes; (void)n_in; (void)out_size; (void)ws_size;
  float* outp = (float*)d_out;

  char* ws = (char*)d_ws;
  size_t off = 0;
  u16* adj_bf = (u16*)(ws + off);               // 88,510,464 B
  u16* logits_bf = adj_bf;                      // overlay (adj dead by then)
  off += (size_t)B_ * NP * NP * 2;
  float* rdenom = (float*)(ws + off); off += (size_t)MTOT * 4;
  u16* zp  = (u16*)(ws + off); off += 256;
  u16* w0t = (u16*)(ws + off); off += 512 * 512 * 2;
  u16* w1t = (u16*)(ws + off); off += 512 * 512 * 2;
  u16* owt = (u16*)(ws + off); off += 512 * 1024 * 2;
  u16* xt  = (u16*)(ws + off); off += (size_t)B_ * 512 * NP * 2;  // x0t / g0t
  u16* S   = (u16*)(ws + off); off += (size_t)MTOT * 512 * 2;
  u16* g0  = (u16*)(ws + off); off += (size_t)MTOT * 512 * 2;
  u16* g1  = (u16*)(ws + off); off += (size_t)MTOT * 512 * 2;

  zero_zp<<<1, 128, 0, stream>>>(zp);
  prep_adj<<<MTOT, 256, 0, stream>>>(adj, adj_bf, rdenom);

  dim3 gT((NP + 63) / 64, D_ / 64, B_);         // (37, 8, 8)
  tcvt<1><<<gT, 256, 0, stream>>>(inputs, xt, NP, D_, (size_t)NP * D_, (size_t)D_ * NP);
  tcvt<1><<<dim3(8, 8, 1),  256, 0, stream>>>(W0w,  w0t, 512,  512, 0, 0);
  tcvt<1><<<dim3(8, 8, 1),  256, 0, stream>>>(W1w,  w1t, 512,  512, 0, 0);
  tcvt<1><<<dim3(16, 8, 1), 256, 0, stream>>>(outw, owt, 1024, 512, 0, 0);

  dim3 gAdj(19, 4, B_);
  dim3 gFlat(147, 4, 1);
  gemm_bf<0><<<gAdj,  256, 0, stream>>>(adj_bf, nullptr, xt,  xt, nullptr, nullptr, zp, S);
  gemm_bf<1><<<gFlat, 256, 0, stream>>>(S, nullptr, w0t, nullptr, W0b, rdenom, zp, g0);
  tcvt<0><<<gT, 256, 0, stream>>>(g0, xt, NP, D_, (size_t)NP * D_, (size_t)D_ * NP);
  gemm_bf<0><<<gAdj,  256, 0, stream>>>(adj_bf, nullptr, xt,  xt, nullptr, nullptr, zp, S);
  gemm_bf<1><<<gFlat, 256, 0, stream>>>(S, nullptr, w1t, nullptr, W1b, rdenom, zp, g1);
  gemm_bf<2><<<gFlat, 256, 0, stream>>>(g0, g1, owt, nullptr, outb, nullptr, zp, logits_bf);

  ner_kernel <<<B_ * SENT, 64,  0, stream>>>(ner, logits_bf, nerw, nerb, outp);
  pair_kernel<<<PAIRS,     256, 0, stream>>>(logits_bf, refeat, rew, reb, ps, hs, ts,
                                             outp + B_ * SENT * NERL);
}

// Round 3
// 430.673 us; speedup vs baseline: 5.3727x; 1.1835x over previous
//
#include <hip/hip_runtime.h>
#include <hip/hip_bf16.h>

#define B_    8
#define NP    2352
#define D_    512
#define SENT  48
#define PAIRS 512
#define NERL  16
#define REL   32
#define MTOT  (B_*NP)   // 18816

typedef unsigned short u16;
typedef __bf16 bf16x8 __attribute__((ext_vector_type(8)));
typedef float  f32x4  __attribute__((ext_vector_type(4)));

__device__ __forceinline__ u16 f2b(float f) {
  union { float f; unsigned u; } c; c.f = f;
  unsigned u = c.u;
  u += 0x7fffu + ((u >> 16) & 1u);           // round-to-nearest-even
  return (u16)(u >> 16);
}
__device__ __forceinline__ float b2f(u16 h) {
  union { unsigned u; float f; } c; c.u = ((unsigned)h) << 16;
  return c.f;
}
__device__ __forceinline__ void gload16(const u16* g, u16* lds) {
  __builtin_amdgcn_global_load_lds(
      (const __attribute__((address_space(1))) unsigned*)g,
      (__attribute__((address_space(3))) unsigned*)lds, 16, 0, 0);
}

// ----------------------------------------------------------------- zero ----
__global__ void zero_zp(u16* zp) { zp[threadIdx.x] = 0; }

// ------------------------------------------------------------- prep_adj ----
// adj f32 -> adj bf16 (same layout) + rdenom = 1/(rowsum+1). One block/row.
__global__ __launch_bounds__(256) void prep_adj(const float* __restrict__ adj,
                                                u16* __restrict__ adjb,
                                                float* __restrict__ rdenom) {
  const int row = blockIdx.x;                 // 0..18815
  const float4* src = (const float4*)(adj + (size_t)row * NP);
  ushort4* dst = (ushort4*)(adjb + (size_t)row * NP);
  float s = 0.f;
  for (int i = threadIdx.x; i < NP / 4; i += 256) {
    float4 v = src[i];
    s += (v.x + v.y) + (v.z + v.w);
    ushort4 o; o.x = f2b(v.x); o.y = f2b(v.y); o.z = f2b(v.z); o.w = f2b(v.w);
    dst[i] = o;
  }
  #pragma unroll
  for (int o = 32; o > 0; o >>= 1) s += __shfl_down(s, o, 64);
  __shared__ float red[4];
  int w = threadIdx.x >> 6, l = threadIdx.x & 63;
  if (l == 0) red[w] = s;
  __syncthreads();
  if (threadIdx.x == 0)
    rdenom[row] = 1.f / (red[0] + red[1] + red[2] + red[3] + 1.f);
}

// ----------------------------------------------------- transpose-convert ---
// in [R][C] (f32 or bf16) -> out [C][R] bf16.  64x64 tiles, 256 threads.
template<int INF32>
__global__ __launch_bounds__(256) void tcvt(const void* __restrict__ in_,
                                            u16* __restrict__ out,
                                            int R, int C, size_t inb, size_t outb) {
  __shared__ u16 tile[64][65];
  const int b  = blockIdx.z;
  const int r0 = blockIdx.x * 64, c0 = blockIdx.y * 64;
  const int t  = threadIdx.x;
  const int tr = t >> 4, tc = (t & 15) * 4;
  #pragma unroll
  for (int i = 0; i < 4; ++i) {
    int rl = i * 16 + tr;
    int r  = r0 + rl;
    if (r < R) {
      if (INF32) {
        const float* in = (const float*)in_ + (size_t)b * inb + (size_t)r * C + c0 + tc;
        float4 v = *(const float4*)in;
        tile[rl][tc + 0] = f2b(v.x); tile[rl][tc + 1] = f2b(v.y);
        tile[rl][tc + 2] = f2b(v.z); tile[rl][tc + 3] = f2b(v.w);
      } else {
        const u16* in = (const u16*)in_ + (size_t)b * inb + (size_t)r * C + c0 + tc;
        ushort4 v = *(const ushort4*)in;
        tile[rl][tc + 0] = v.x; tile[rl][tc + 1] = v.y;
        tile[rl][tc + 2] = v.z; tile[rl][tc + 3] = v.w;
      }
    }
  }
  __syncthreads();
  const int c  = t >> 2;
  const int rb = (t & 3) * 16;
  u16* orow = out + (size_t)b * outb + (size_t)(c0 + c) * R + r0;
  #pragma unroll
  for (int i = 0; i < 4; ++i) {
    int rl = rb + i * 4;
    int r  = r0 + rl;
    if (r + 3 < R) {
      ushort4 v;
      v.x = tile[rl + 0][c]; v.y = tile[rl + 1][c];
      v.z = tile[rl + 2][c]; v.w = tile[rl + 3][c];
      *(ushort4*)(orow + rl) = v;
    } else {
      for (int j = 0; j < 4; ++j)
        if (r + j < R) orow[rl + j] = tile[rl + j][c];
    }
  }
}

// ------------------------------------------------------------- MFMA GEMM ---
// C[m][n] = sum_k A[m][k]*B[n][k]  (both operands k-major), 128x128 tile,
// BK=32, 4 waves (2x2), each wave 64x64 via 4x4 16x16x32 bf16 MFMA frags.
// Triple-buffered LDS, stage issued 2 K-steps ahead, counted vmcnt(4),
// raw s_barrier (no full drain).  1D grid, XCD-chunked swizzle, n fastest.
// MODE 0: adj GEMM  (per-batch; epilogue += x from Xt; out bf16 S)
// MODE 1: W GEMM    (epilogue (acc+2b)*rdenom, relu; out bf16 g)
// MODE 2: cat GEMM  (A = concat(g0,g1) over k; epilogue +bias; out bf16)
template<int MODE>
__global__ __launch_bounds__(256) void gemm_bf(
    const u16* __restrict__ A, const u16* __restrict__ A2,
    const u16* __restrict__ Bm, const u16* __restrict__ Xt,
    const float* __restrict__ bias, const float* __restrict__ rdenom,
    const u16* __restrict__ zp, u16* __restrict__ out)
{
  constexpr int KACT   = (MODE == 0) ? NP : (MODE == 1 ? 512 : 1024);
  constexpr int KSTEPS = (KACT + 31) / 32;
  constexpr int LDB    = KACT;
  constexpr int LDA    = (MODE == 0) ? NP : 512;

  // ---- XCD-chunked block swizzle, n-tile fastest within a chunk
  int m0, n0;
  const u16* Ab = A;
  const u16* Bb = Bm;
  const u16* Xb = Xt;
  size_t outBase = 0;
  if constexpr (MODE == 0) {
    // grid = 608 = 8 XCD chunks of 76 (one batch each); local: n fastest
    const int orig = blockIdx.x;
    const int rid  = (orig & 7) * 76 + (orig >> 3);
    const int b    = rid / 76;
    const int loc  = rid - b * 76;
    n0 = (loc & 3) * 128;
    m0 = (loc >> 2) * 128;
    Ab = A  + (size_t)b * NP * NP;
    Bb = Bm + (size_t)b * 512 * NP;
    Xb = Xt + (size_t)b * 512 * NP;
    outBase = (size_t)b * NP * 512;
  } else {
    // grid = 588; bijective m204 chunking (q=73, r=4), n fastest
    const int orig = blockIdx.x;
    const int xcd = orig & 7, pos = orig >> 3;
    const int base = (xcd < 4) ? xcd * 74 : 296 + (xcd - 4) * 73;
    const int rid = base + pos;
    n0 = (rid & 3) * 128;
    m0 = (rid >> 2) * 128;
  }

  __shared__ u16 As[3 * 4096];   // 3 bufs x [128 rows][32 k], k-slot swizzled
  __shared__ u16 Bs[3 * 4096];

  const int t  = threadIdx.x;
  const int w  = t >> 6, l = t & 63;
  const int wm = w >> 1, wn = w & 1;
  const int lr = l & 15, lq = l >> 4;

  f32x4 acc[4][4];
  #pragma unroll
  for (int i = 0; i < 4; ++i)
    #pragma unroll
    for (int j = 0; j < 4; ++j)
      acc[i][j] = (f32x4){0.f, 0.f, 0.f, 0.f};

  const int rA = w * 16 + (l >> 2);   // local row staged by this lane (issue 0)
  const int sl = l & 3;               // k-slot (pre-swizzle)

  auto STAGE = [&](int buf, int ks) {
    const int k0 = ks * 32;
    #pragma unroll
    for (int i = 0; i < 2; ++i) {
      const int r  = i * 64 + rA;                         // 0..127
      const int gk = k0 + ((sl ^ ((r >> 1) & 3)) << 3);   // swizzled source k
      { // ---- A tile
        int gm = m0 + r;
        if (MODE == 0 && gm > NP - 1) gm = NP - 1;        // M-tail clamp
        const u16* src;
        if constexpr (MODE == 2) {
          src = (gk < 512) ? (A  + (size_t)gm * 512 + gk)
                           : (A2 + (size_t)gm * 512 + (gk - 512));
        } else {
          src = Ab + (size_t)gm * LDA + gk;
        }
        if (gk >= KACT) src = zp;                         // K-tail -> zeros
        gload16(src, As + buf * 4096 + i * 2048 + w * 512);
      }
      { // ---- B tile
        const int gn = n0 + r;
        const u16* src = Bb + (size_t)gn * LDB + gk;
        if (gk >= KACT) src = zp;
        gload16(src, Bs + buf * 4096 + i * 2048 + w * 512);
      }
    }
  };

  // prologue: stage K-steps 0 and 1
  STAGE(0, 0);
  if (KSTEPS > 1) STAGE(1, 1);
  asm volatile("s_waitcnt vmcnt(4)" ::: "memory");        // buf0 landed
  __builtin_amdgcn_s_barrier();

  int bufc = 0;
  for (int ks = 0; ks < KSTEPS; ++ks) {
    if (ks + 2 < KSTEPS) {
      int bufs = bufc + 2; if (bufs >= 3) bufs -= 3;
      STAGE(bufs, ks + 2);
    }
    const u16* Ac = As + bufc * 4096;
    const u16* Bc = Bs + bufc * 4096;
    bf16x8 af[4], bg[4];
    #pragma unroll
    for (int f = 0; f < 4; ++f) {
      const int ra = wm * 64 + f * 16 + lr;
      af[f] = *(const bf16x8*)(Ac + ra * 32 + ((lq ^ ((ra >> 1) & 3)) << 3));
      const int rb2 = wn * 64 + f * 16 + lr;
      bg[f] = *(const bf16x8*)(Bc + rb2 * 32 + ((lq ^ ((rb2 >> 1) & 3)) << 3));
    }
    #pragma unroll
    for (int mf = 0; mf < 4; ++mf)
      #pragma unroll
      for (int nf = 0; nf < 4; ++nf)
        acc[mf][nf] = __builtin_amdgcn_mfma_f32_16x16x32_bf16(
            af[mf], bg[nf], acc[mf][nf], 0, 0, 0);
    // next buffer (staged at iter ks-1) must be landed; keep the 4 loads
    // just issued (for ks+2) in flight.
    if (ks + 2 < KSTEPS) asm volatile("s_waitcnt vmcnt(4)" ::: "memory");
    else                 asm volatile("s_waitcnt vmcnt(0)" ::: "memory");
    __builtin_amdgcn_s_barrier();
    bufc = (bufc == 2) ? 0 : bufc + 1;
  }

  // --------------------------------------------------------- epilogue ----
  #pragma unroll
  for (int mf = 0; mf < 4; ++mf) {
    const int gm0 = m0 + wm * 64 + mf * 16 + lq * 4;
    f32x4 rd;
    if constexpr (MODE == 1) rd = *(const f32x4*)(rdenom + gm0);
    #pragma unroll
    for (int nf = 0; nf < 4; ++nf) {
      const int gn = n0 + wn * 64 + nf * 16 + lr;
      if constexpr (MODE == 0) {
        const int xg = (gm0 > NP - 4) ? (NP - 4) : gm0;
        ushort4 xv = *(const ushort4*)(Xb + (size_t)gn * NP + xg);
        float xf[4] = {b2f(xv.x), b2f(xv.y), b2f(xv.z), b2f(xv.w)};
        #pragma unroll
        for (int r = 0; r < 4; ++r) {
          const int gm = gm0 + r;
          if (gm < NP)
            out[outBase + (size_t)gm * 512 + gn] = f2b(acc[mf][nf][r] + xf[r]);
        }
      } else if constexpr (MODE == 1) {
        const float bn = 2.f * bias[gn];
        #pragma unroll
        for (int r = 0; r < 4; ++r) {
          float v = (acc[mf][nf][r] + bn) * rd[r];
          v = fmaxf(v, 0.f);
          out[(size_t)(gm0 + r) * 512 + gn] = f2b(v);
        }
      } else {
        const float bn = bias[gn];
        #pragma unroll
        for (int r = 0; r < 4; ++r)
          out[(size_t)(gm0 + r) * 512 + gn] = f2b(acc[mf][nf][r] + bn);
      }
    }
  }
}

// ------------------------------------------------------------- ner head ----
__global__ __launch_bounds__(64) void ner_kernel(const float* __restrict__ ner,
                                                 const u16* __restrict__ logits,
                                                 const float* __restrict__ nw,
                                                 const float* __restrict__ nb,
                                                 float* __restrict__ out) {
  int r = blockIdx.x;                 // 0..383
  int b = r / SENT, tp = r % SENT;
  int lane = threadIdx.x;
  const float* nrow = ner    + ((size_t)b * SENT + tp) * D_;
  const u16*   lrow = logits + ((size_t)b * NP   + tp) * D_;
  float rv[16];
  #pragma unroll
  for (int i = 0; i < 8; ++i) rv[i]     = nrow[lane + i * 64];
  #pragma unroll
  for (int i = 0; i < 8; ++i) rv[8 + i] = b2f(lrow[lane + i * 64]);
  for (int j = 0; j < NERL; ++j) {
    float s = 0.f;
    #pragma unroll
    for (int i = 0; i < 16; ++i)
      s = fmaf(rv[i], nw[(size_t)(lane + i * 64) * NERL + j], s);
    for (int o = 32; o > 0; o >>= 1) s += __shfl_down(s, o);
    if (lane == 0) out[r * NERL + j] = s + nb[j];
  }
}

// ----------------------------------------------------------- pair + re -----
__global__ __launch_bounds__(256) void pair_kernel(const u16* __restrict__ logits,
                                                   const float* __restrict__ refeat,
                                                   const float* __restrict__ rw,
                                                   const float* __restrict__ rb,
                                                   const int* __restrict__ ps,
                                                   const int* __restrict__ hs,
                                                   const int* __restrict__ ts,
                                                   float* __restrict__ out) {
  int p = blockIdx.x;
  __shared__ float avg[D_];
  int b = ps[p], h = hs[p], tt = ts[p];
  const u16* base = logits + (size_t)b * NP * D_;
  const u16* r00 = base + (size_t)((h + 1) * SENT + tt) * D_;
  const u16* r01 = base + (size_t)((h + 1) * SENT + tt + 1) * D_;
  const u16* r10 = base + (size_t)((h + 2) * SENT + tt) * D_;
  const u16* r11 = base + (size_t)((h + 2) * SENT + tt + 1) * D_;
  for (int d = threadIdx.x; d < D_; d += 256)
    avg[d] = 0.25f * (b2f(r00[d]) + b2f(r01[d]) + b2f(r10[d]) + b2f(r11[d]));
  __syncthreads();
  int wave = threadIdx.x >> 6, lane = threadIdx.x & 63;
  const float* rf = refeat + (size_t)p * D_;
  for (int jj = 0; jj < 8; ++jj) {
    int j = wave * 8 + jj;
    float s = 0.f;
    #pragma unroll
    for (int i = 0; i < 8; ++i) {
      int k = lane + i * 64;
      s = fmaf(rf[k],  rw[(size_t)k * REL + j], s);
      s = fmaf(avg[k], rw[(size_t)(k + D_) * REL + j], s);
    }
    for (int o = 32; o > 0; o >>= 1) s += __shfl_down(s, o);
    if (lane == 0) out[p * REL + j] = s + rb[j];
  }
}

// --------------------------------------------------------------- launch ----
extern "C" void kernel_launch(void* const* d_in, const int* in_sizes, int n_in,
                              void* d_out, int out_size, void* d_ws, size_t ws_size,
                              hipStream_t stream) {
  const float* inputs = (const float*)d_in[0];
  const float* ner    = (const float*)d_in[1];
  const float* refeat = (const float*)d_in[2];
  const float* adj    = (const float*)d_in[3];
  const float* W0w    = (const float*)d_in[4];
  const float* W0b    = (const float*)d_in[5];
  const float* W1w    = (const float*)d_in[6];
  const float* W1b    = (const float*)d_in[7];
  const float* outw   = (const float*)d_in[8];
  const float* outb   = (const float*)d_in[9];
  const float* nerw   = (const float*)d_in[10];
  const float* nerb   = (const float*)d_in[11];
  const float* rew    = (const float*)d_in[12];
  const float* reb    = (const float*)d_in[13];
  const int*   ps     = (const int*)d_in[14];
  const int*   hs     = (const int*)d_in[15];
  const int*   ts     = (const int*)d_in[16];
  (void)in_sizes; (void)n_in; (void)out_size; (void)ws_size;
  float* outp = (float*)d_out;

  char* ws = (char*)d_ws;
  size_t off = 0;
  u16* adj_bf = (u16*)(ws + off);               // 88,510,464 B
  u16* logits_bf = adj_bf;                      // overlay (adj dead by then)
  off += (size_t)B_ * NP * NP * 2;
  float* rdenom = (float*)(ws + off); off += (size_t)MTOT * 4;
  u16* zp  = (u16*)(ws + off); off += 256;
  u16* w0t = (u16*)(ws + off); off += 512 * 512 * 2;
  u16* w1t = (u16*)(ws + off); off += 512 * 512 * 2;
  u16* owt = (u16*)(ws + off); off += 512 * 1024 * 2;
  u16* xt  = (u16*)(ws + off); off += (size_t)B_ * 512 * NP * 2;  // x0t / g0t
  u16* S   = (u16*)(ws + off); off += (size_t)MTOT * 512 * 2;
  u16* g0  = (u16*)(ws + off); off += (size_t)MTOT * 512 * 2;
  u16* g1  = (u16*)(ws + off); off += (size_t)MTOT * 512 * 2;

  zero_zp<<<1, 128, 0, stream>>>(zp);
  prep_adj<<<MTOT, 256, 0, stream>>>(adj, adj_bf, rdenom);

  dim3 gT((NP + 63) / 64, D_ / 64, B_);         // (37, 8, 8)
  tcvt<1><<<gT, 256, 0, stream>>>(inputs, xt, NP, D_, (size_t)NP * D_, (size_t)D_ * NP);
  tcvt<1><<<dim3(8, 8, 1),  256, 0, stream>>>(W0w,  w0t, 512,  512, 0, 0);
  tcvt<1><<<dim3(8, 8, 1),  256, 0, stream>>>(W1w,  w1t, 512,  512, 0, 0);
  tcvt<1><<<dim3(16, 8, 1), 256, 0, stream>>>(outw, owt, 1024, 512, 0, 0);

  gemm_bf<0><<<608, 256, 0, stream>>>(adj_bf, nullptr, xt,  xt, nullptr, nullptr, zp, S);
  gemm_bf<1><<<588, 256, 0, stream>>>(S, nullptr, w0t, nullptr, W0b, rdenom, zp, g0);
  tcvt<0><<<gT, 256, 0, stream>>>(g0, xt, NP, D_, (size_t)NP * D_, (size_t)D_ * NP);
  gemm_bf<0><<<608, 256, 0, stream>>>(adj_bf, nullptr, xt,  xt, nullptr, nullptr, zp, S);
  gemm_bf<1><<<588, 256, 0, stream>>>(S, nullptr, w1t, nullptr, W1b, rdenom, zp, g1);
  gemm_bf<2><<<588, 256, 0, stream>>>(g0, g1, owt, nullptr, outb, nullptr, zp, logits_bf);

  ner_kernel <<<B_ * SENT, 64,  0, stream>>>(ner, logits_bf, nerw, nerb, outp);
  pair_kernel<<<PAIRS,     256, 0, stream>>>(logits_bf, refeat, rew, reb, ps, hs, ts,
                                             outp + B_ * SENT * NERL);
}

// Round 4
// 408.739 us; speedup vs baseline: 5.6611x; 1.0537x over previous
//
#include <hip/hip_runtime.h>
#include <hip/hip_bf16.h>

#define B_    8
#define NP    2352
#define D_    512
#define SENT  48
#define PAIRS 512
#define NERL  16
#define REL   32
#define MTOT  (B_*NP)   // 18816

typedef unsigned short u16;
typedef __bf16 bf16x8 __attribute__((ext_vector_type(8)));
typedef float  f32x4  __attribute__((ext_vector_type(4)));

__device__ __forceinline__ u16 f2b(float f) {
  union { float f; unsigned u; } c; c.f = f;
  unsigned u = c.u;
  u += 0x7fffu + ((u >> 16) & 1u);           // round-to-nearest-even
  return (u16)(u >> 16);
}
__device__ __forceinline__ float b2f(u16 h) {
  union { unsigned u; float f; } c; c.u = ((unsigned)h) << 16;
  return c.f;
}
__device__ __forceinline__ void gload16(const u16* g, u16* lds) {
  __builtin_amdgcn_global_load_lds(
      (const __attribute__((address_space(1))) unsigned*)g,
      (__attribute__((address_space(3))) unsigned*)lds, 16, 0, 0);
}

// ----------------------------------------------------------------- zero ----
__global__ void zero_zp(u16* zp) { zp[threadIdx.x] = 0; }

// ------------------------------------------------------------- prep_adj ----
// adj f32 -> adj bf16 (same layout) + rdenom = 1/(rowsum+1). One block/row.
__global__ __launch_bounds__(256) void prep_adj(const float* __restrict__ adj,
                                                u16* __restrict__ adjb,
                                                float* __restrict__ rdenom) {
  const int row = blockIdx.x;                 // 0..18815
  const float4* src = (const float4*)(adj + (size_t)row * NP);
  ushort4* dst = (ushort4*)(adjb + (size_t)row * NP);
  float s = 0.f;
  for (int i = threadIdx.x; i < NP / 4; i += 256) {
    float4 v = src[i];
    s += (v.x + v.y) + (v.z + v.w);
    ushort4 o; o.x = f2b(v.x); o.y = f2b(v.y); o.z = f2b(v.z); o.w = f2b(v.w);
    dst[i] = o;
  }
  #pragma unroll
  for (int o = 32; o > 0; o >>= 1) s += __shfl_down(s, o, 64);
  __shared__ float red[4];
  int w = threadIdx.x >> 6, l = threadIdx.x & 63;
  if (l == 0) red[w] = s;
  __syncthreads();
  if (threadIdx.x == 0)
    rdenom[row] = 1.f / (red[0] + red[1] + red[2] + red[3] + 1.f);
}

// ----------------------------------------------------- transpose-convert ---
// in [R][C] f32 -> out [C][R] bf16.  64x64 tiles, 256 threads.
__global__ __launch_bounds__(256) void tcvt(const float* __restrict__ in_,
                                            u16* __restrict__ out,
                                            int R, int C, size_t inb, size_t outb) {
  __shared__ u16 tile[64][65];
  const int b  = blockIdx.z;
  const int r0 = blockIdx.x * 64, c0 = blockIdx.y * 64;
  const int t  = threadIdx.x;
  const int tr = t >> 4, tc = (t & 15) * 4;
  #pragma unroll
  for (int i = 0; i < 4; ++i) {
    int rl = i * 16 + tr;
    int r  = r0 + rl;
    if (r < R) {
      const float* in = in_ + (size_t)b * inb + (size_t)r * C + c0 + tc;
      float4 v = *(const float4*)in;
      tile[rl][tc + 0] = f2b(v.x); tile[rl][tc + 1] = f2b(v.y);
      tile[rl][tc + 2] = f2b(v.z); tile[rl][tc + 3] = f2b(v.w);
    }
  }
  __syncthreads();
  const int c  = t >> 2;
  const int rb = (t & 3) * 16;
  u16* orow = out + (size_t)b * outb + (size_t)(c0 + c) * R + r0;
  #pragma unroll
  for (int i = 0; i < 4; ++i) {
    int rl = rb + i * 4;
    int r  = r0 + rl;
    if (r + 3 < R) {
      ushort4 v;
      v.x = tile[rl + 0][c]; v.y = tile[rl + 1][c];
      v.z = tile[rl + 2][c]; v.w = tile[rl + 3][c];
      *(ushort4*)(orow + rl) = v;
    } else {
      for (int j = 0; j < 4; ++j)
        if (r + j < R) orow[rl + j] = tile[rl + j][c];
    }
  }
}

// -------------------------------------------------- 8-wave 256x256 GEMM ----
// C[m][n] = sum_k A[m][k]*B[n][k] (both k-major). BM=BN=256, BK=32, 512 thr,
// 8 waves (2m x 4n), per-wave 128x64 (8x4 frags of 16x16x32 bf16).
// 4-deep LDS ring (128 KB); per K-tile 2 phases:
//   ph1: ds_read A(qm0)+B, issue STAGE_A(t+3), barrier, lgkm, 16 MFMA
//   ph2: ds_read A(qm1),   issue STAGE_B(t+3), barrier, lgkm, 16 MFMA,
//        vmcnt(8) [forces tile t+1 landed; never drains], barrier
// LDS chunk swizzle: slot = chunk ^ ((row>>1)&3), applied on BOTH sides
// (pre-swizzled global source + swizzled ds_read) -> 2-way banks = free.
// K-tail and t+3 overrun redirect to a zero page at 16B granularity.
// MODE 0: S=adj@X^T (+x epilogue, per-batch)  MODE 1: (S@W+2b)*rdenom,relu
// MODE 2: concat(g0,g1)@outw + b.  WRITE_T: also emit transposed bf16 out.
template<int MODE, int WRITE_T>
__global__ __launch_bounds__(512, 2) void gemm8(
    const u16* __restrict__ A, const u16* __restrict__ A2,
    const u16* __restrict__ Bm, const u16* __restrict__ Xt,
    const float* __restrict__ bias, const float* __restrict__ rdenom,
    const u16* __restrict__ zp, u16* __restrict__ out, u16* __restrict__ outT)
{
  constexpr int KACT   = (MODE == 0) ? NP : (MODE == 1 ? 512 : 1024);
  constexpr int KTILES = (KACT + 31) / 32;     // 74 / 16 / 32
  constexpr int LDA    = (MODE == 0) ? NP : 512;
  constexpr int LDB    = KACT;

  int m0, n0;
  const u16* Ab = A;
  const u16* Bb = Bm;
  const u16* Xb = Xt;
  size_t outBase = 0;
  int bat = 0;
  if constexpr (MODE == 0) {
    // grid 160 = 8 XCD chunks of 20 (one batch each); within: m-major, n fast
    const int bx = blockIdx.x;
    bat = bx & 7;
    const int loc = bx >> 3;            // 0..19
    const int mt = loc >> 1;
    n0 = (loc & 1) << 8;
    m0 = (mt < 9) ? mt * 256 : NP - 256;          // overlap last tile
    Ab = A  + (size_t)bat * NP * NP;
    Bb = Bm + (size_t)bat * 512 * NP;
    Xb = Xt + (size_t)bat * 512 * NP;
    outBase = (size_t)bat * NP * 512;
  } else {
    // grid 148; bijective XCD chunking (q=18, r=4)
    const int bx = blockIdx.x;
    const int xcd = bx & 7, pos = bx >> 3;
    const int rid = (xcd < 4) ? xcd * 19 + pos : 76 + (xcd - 4) * 18 + pos;
    const int mt = rid >> 1;
    n0 = (rid & 1) << 8;
    m0 = (mt < 73) ? mt * 256 : MTOT - 256;       // overlap last tile
  }

  __shared__ __align__(16) u16 As[4 * 8192];   // 4 bufs x 256 rows x 32 k
  __shared__ __align__(16) u16 Bs[4 * 8192];

  const int tid = threadIdx.x;
  const int l  = tid & 63;
  const int w  = tid >> 6;
  const int wm = w >> 2, wn = w & 3;
  const int lr = l & 15, lq = l >> 4;

  f32x4 acc[8][4];
  #pragma unroll
  for (int i = 0; i < 8; ++i)
    #pragma unroll
    for (int j = 0; j < 4; ++j)
      acc[i][j] = (f32x4){0.f, 0.f, 0.f, 0.f};

  auto STAGE_A = [&](int buf, int kt) {
    #pragma unroll
    for (int j = 0; j < 2; ++j) {
      const int cl  = j * 512 + tid;            // 0..1023
      const int row = cl >> 2, c = cl & 3;
      const int gch = kt * 4 + (c ^ ((row >> 1) & 3));  // logical 16B chunk
      const int gm  = m0 + row;                 // always in-range (overlap)
      const u16* src;
      if constexpr (MODE == 2) {
        src = (gch < 64) ? A  + (size_t)gm * 512 + gch * 8
                         : A2 + (size_t)gm * 512 + (gch - 64) * 8;
      } else {
        src = Ab + (size_t)gm * LDA + gch * 8;
      }
      if (gch * 8 + 8 > KACT) src = zp;         // k-tail / lookahead -> zeros
      gload16(src, As + buf * 8192 + cl * 8);
    }
  };
  auto STAGE_B = [&](int buf, int kt) {
    #pragma unroll
    for (int j = 0; j < 2; ++j) {
      const int cl  = j * 512 + tid;
      const int row = cl >> 2, c = cl & 3;
      const int gch = kt * 4 + (c ^ ((row >> 1) & 3));
      const int gn  = n0 + row;
      const u16* src = Bb + (size_t)gn * LDB + gch * 8;
      if (gch * 8 + 8 > KACT) src = zp;
      gload16(src, Bs + buf * 8192 + cl * 8);
    }
  };

  // prologue: tiles 0,1,2 staged (12 instr/thread in flight)
  STAGE_A(0, 0); STAGE_B(0, 0);
  STAGE_A(1, 1); STAGE_B(1, 1);
  STAGE_A(2, 2); STAGE_B(2, 2);
  asm volatile("s_waitcnt vmcnt(8)" ::: "memory");   // tile 0 landed
  __builtin_amdgcn_s_barrier();

  for (int kt = 0; kt < KTILES; ++kt) {
    const int buf = kt & 3;
    const u16* Ac = As + buf * 8192;
    const u16* Bc = Bs + buf * 8192;
    bf16x8 af[4], bg[4];
    // ---------------- phase 1: qm0 + all B, stage A(kt+3) ----------------
    #pragma unroll
    for (int f = 0; f < 4; ++f) {
      const int ra = wm * 128 + f * 16 + lr;
      af[f] = *(const bf16x8*)(Ac + ra * 32 + ((lq ^ ((ra >> 1) & 3)) << 3));
      const int rb = wn * 64 + f * 16 + lr;
      bg[f] = *(const bf16x8*)(Bc + rb * 32 + ((lq ^ ((rb >> 1) & 3)) << 3));
    }
    STAGE_A((kt + 3) & 3, kt + 3);
    __builtin_amdgcn_s_barrier();
    asm volatile("s_waitcnt lgkmcnt(0)" ::: "memory");
    __builtin_amdgcn_s_setprio(1);
    #pragma unroll
    for (int mf = 0; mf < 4; ++mf)
      #pragma unroll
      for (int nf = 0; nf < 4; ++nf)
        acc[mf][nf] = __builtin_amdgcn_mfma_f32_16x16x32_bf16(
            af[mf], bg[nf], acc[mf][nf], 0, 0, 0);
    __builtin_amdgcn_s_setprio(0);
    __builtin_amdgcn_s_barrier();
    // ---------------- phase 2: qm1 (B reused), stage B(kt+3) -------------
    #pragma unroll
    for (int f = 0; f < 4; ++f) {
      const int ra = wm * 128 + 64 + f * 16 + lr;
      af[f] = *(const bf16x8*)(Ac + ra * 32 + ((lq ^ ((ra >> 1) & 3)) << 3));
    }
    STAGE_B((kt + 3) & 3, kt + 3);
    __builtin_amdgcn_s_barrier();
    asm volatile("s_waitcnt lgkmcnt(0)" ::: "memory");
    __builtin_amdgcn_s_setprio(1);
    #pragma unroll
    for (int mf = 0; mf < 4; ++mf)
      #pragma unroll
      for (int nf = 0; nf < 4; ++nf)
        acc[4 + mf][nf] = __builtin_amdgcn_mfma_f32_16x16x32_bf16(
            af[mf], bg[nf], acc[4 + mf][nf], 0, 0, 0);
    __builtin_amdgcn_s_setprio(0);
    asm volatile("s_waitcnt vmcnt(8)" ::: "memory");  // tile kt+1 landed
    __builtin_amdgcn_s_barrier();
  }

  // --------------------------------------------------------- epilogue ----
  #pragma unroll
  for (int mf = 0; mf < 8; ++mf) {
    const int gm0 = m0 + wm * 128 + mf * 16 + lq * 4;
    f32x4 rd;
    if constexpr (MODE == 1) rd = *(const f32x4*)(rdenom + gm0);
    #pragma unroll
    for (int nf = 0; nf < 4; ++nf) {
      const int gn = n0 + wn * 64 + nf * 16 + lr;
      u16 ov[4];
      if constexpr (MODE == 0) {
        ushort4 xv = *(const ushort4*)(Xb + (size_t)gn * NP + gm0);
        const float xf[4] = {b2f(xv.x), b2f(xv.y), b2f(xv.z), b2f(xv.w)};
        #pragma unroll
        for (int r = 0; r < 4; ++r) ov[r] = f2b(acc[mf][nf][r] + xf[r]);
      } else if constexpr (MODE == 1) {
        const float bn = 2.f * bias[gn];
        #pragma unroll
        for (int r = 0; r < 4; ++r)
          ov[r] = f2b(fmaxf((acc[mf][nf][r] + bn) * rd[r], 0.f));
      } else {
        const float bn = bias[gn];
        #pragma unroll
        for (int r = 0; r < 4; ++r) ov[r] = f2b(acc[mf][nf][r] + bn);
      }
      #pragma unroll
      for (int r = 0; r < 4; ++r)
        out[outBase + (size_t)(gm0 + r) * 512 + gn] = ov[r];
      if constexpr (WRITE_T) {
        const int bb = gm0 / NP;                 // batch of this row-quad
        const int ml = gm0 - bb * NP;
        ushort4 tv; tv.x = ov[0]; tv.y = ov[1]; tv.z = ov[2]; tv.w = ov[3];
        *(ushort4*)(outT + ((size_t)bb * 512 + gn) * NP + ml) = tv;
      }
    }
  }
}

// ------------------------------------------------------------- ner head ----
__global__ __launch_bounds__(64) void ner_kernel(const float* __restrict__ ner,
                                                 const u16* __restrict__ logits,
                                                 const float* __restrict__ nw,
                                                 const float* __restrict__ nb,
                                                 float* __restrict__ out) {
  int r = blockIdx.x;                 // 0..383
  int b = r / SENT, tp = r % SENT;
  int lane = threadIdx.x;
  const float* nrow = ner    + ((size_t)b * SENT + tp) * D_;
  const u16*   lrow = logits + ((size_t)b * NP   + tp) * D_;
  float rv[16];
  #pragma unroll
  for (int i = 0; i < 8; ++i) rv[i]     = nrow[lane + i * 64];
  #pragma unroll
  for (int i = 0; i < 8; ++i) rv[8 + i] = b2f(lrow[lane + i * 64]);
  for (int j = 0; j < NERL; ++j) {
    float s = 0.f;
    #pragma unroll
    for (int i = 0; i < 16; ++i)
      s = fmaf(rv[i], nw[(size_t)(lane + i * 64) * NERL + j], s);
    for (int o = 32; o > 0; o >>= 1) s += __shfl_down(s, o);
    if (lane == 0) out[r * NERL + j] = s + nb[j];
  }
}

// ----------------------------------------------------------- pair + re -----
__global__ __launch_bounds__(256) void pair_kernel(const u16* __restrict__ logits,
                                                   const float* __restrict__ refeat,
                                                   const float* __restrict__ rw,
                                                   const float* __restrict__ rb,
                                                   const int* __restrict__ ps,
                                                   const int* __restrict__ hs,
                                                   const int* __restrict__ ts,
                                                   float* __restrict__ out) {
  int p = blockIdx.x;
  __shared__ float avg[D_];
  int b = ps[p], h = hs[p], tt = ts[p];
  const u16* base = logits + (size_t)b * NP * D_;
  const u16* r00 = base + (size_t)((h + 1) * SENT + tt) * D_;
  const u16* r01 = base + (size_t)((h + 1) * SENT + tt + 1) * D_;
  const u16* r10 = base + (size_t)((h + 2) * SENT + tt) * D_;
  const u16* r11 = base + (size_t)((h + 2) * SENT + tt + 1) * D_;
  for (int d = threadIdx.x; d < D_; d += 256)
    avg[d] = 0.25f * (b2f(r00[d]) + b2f(r01[d]) + b2f(r10[d]) + b2f(r11[d]));
  __syncthreads();
  int wave = threadIdx.x >> 6, lane = threadIdx.x & 63;
  const float* rf = refeat + (size_t)p * D_;
  for (int jj = 0; jj < 8; ++jj) {
    int j = wave * 8 + jj;
    float s = 0.f;
    #pragma unroll
    for (int i = 0; i < 8; ++i) {
      int k = lane + i * 64;
      s = fmaf(rf[k],  rw[(size_t)k * REL + j], s);
      s = fmaf(avg[k], rw[(size_t)(k + D_) * REL + j], s);
    }
    for (int o = 32; o > 0; o >>= 1) s += __shfl_down(s, o);
    if (lane == 0) out[p * REL + j] = s + rb[j];
  }
}

// --------------------------------------------------------------- launch ----
extern "C" void kernel_launch(void* const* d_in, const int* in_sizes, int n_in,
                              void* d_out, int out_size, void* d_ws, size_t ws_size,
                              hipStream_t stream) {
  const float* inputs = (const float*)d_in[0];
  const float* ner    = (const float*)d_in[1];
  const float* refeat = (const float*)d_in[2];
  const float* adj    = (const float*)d_in[3];
  const float* W0w    = (const float*)d_in[4];
  const float* W0b    = (const float*)d_in[5];
  const float* W1w    = (const float*)d_in[6];
  const float* W1b    = (const float*)d_in[7];
  const float* outw   = (const float*)d_in[8];
  const float* outb   = (const float*)d_in[9];
  const float* nerw   = (const float*)d_in[10];
  const float* nerb   = (const float*)d_in[11];
  const float* rew    = (const float*)d_in[12];
  const float* reb    = (const float*)d_in[13];
  const int*   ps     = (const int*)d_in[14];
  const int*   hs     = (const int*)d_in[15];
  const int*   ts     = (const int*)d_in[16];
  (void)in_sizes; (void)n_in; (void)out_size; (void)ws_size;
  float* outp = (float*)d_out;

  char* ws = (char*)d_ws;
  size_t off = 0;
  u16* adj_bf = (u16*)(ws + off);               // 88,510,464 B
  u16* logits_bf = adj_bf;                      // overlay (adj dead by then)
  off += (size_t)B_ * NP * NP * 2;
  float* rdenom = (float*)(ws + off); off += (size_t)MTOT * 4;
  u16* zp  = (u16*)(ws + off); off += 512;
  u16* w0t = (u16*)(ws + off); off += 512 * 512 * 2;
  u16* w1t = (u16*)(ws + off); off += 512 * 512 * 2;
  u16* owt = (u16*)(ws + off); off += 512 * 1024 * 2;
  u16* xt  = (u16*)(ws + off); off += (size_t)B_ * 512 * NP * 2;  // x0t / g0t
  u16* S   = (u16*)(ws + off); off += (size_t)MTOT * 512 * 2;
  u16* g0  = (u16*)(ws + off); off += (size_t)MTOT * 512 * 2;
  u16* g1  = (u16*)(ws + off); off += (size_t)MTOT * 512 * 2;

  zero_zp<<<1, 256, 0, stream>>>(zp);
  prep_adj<<<MTOT, 256, 0, stream>>>(adj, adj_bf, rdenom);

  dim3 gT((NP + 63) / 64, D_ / 64, B_);         // (37, 8, 8)
  tcvt<<<gT, 256, 0, stream>>>(inputs, xt, NP, D_, (size_t)NP * D_, (size_t)D_ * NP);
  tcvt<<<dim3(8, 8, 1),  256, 0, stream>>>(W0w,  w0t, 512,  512, 0, 0);
  tcvt<<<dim3(8, 8, 1),  256, 0, stream>>>(W1w,  w1t, 512,  512, 0, 0);
  tcvt<<<dim3(16, 8, 1), 256, 0, stream>>>(outw, owt, 1024, 512, 0, 0);

  gemm8<0,0><<<160, 512, 0, stream>>>(adj_bf, nullptr, xt, xt,
                                      nullptr, nullptr, zp, S, nullptr);
  gemm8<1,1><<<148, 512, 0, stream>>>(S, nullptr, w0t, nullptr,
                                      W0b, rdenom, zp, g0, xt);
  gemm8<0,0><<<160, 512, 0, stream>>>(adj_bf, nullptr, xt, xt,
                                      nullptr, nullptr, zp, S, nullptr);
  gemm8<1,0><<<148, 512, 0, stream>>>(S, nullptr, w1t, nullptr,
                                      W1b, rdenom, zp, g1, nullptr);
  gemm8<2,0><<<148, 512, 0, stream>>>(g0, g1, owt, nullptr,
                                      outb, nullptr, zp, logits_bf, nullptr);

  ner_kernel <<<B_ * SENT, 64,  0, stream>>>(ner, logits_bf, nerw, nerb, outp);
  pair_kernel<<<PAIRS,     256, 0, stream>>>(logits_bf, refeat, rew, reb, ps, hs, ts,
                                             outp + B_ * SENT * NERL);
}